// Round 3
// baseline (100.253 us; speedup 1.0000x reference)
//
#include <hip/hip_runtime.h>

#define IS 256
#define FCOUNT 4096
#define NEARP 0.1f
#define FARP 100.0f
#define TINYF 1e-12f
#define CAP_T 320        // per-16x16-tile LDS list capacity (mean ~60; >5x margin)
#define DET_GLOBAL 1e-5f // |det| below this -> treat as covering all quadrants
#define ZEPS 2e-4f       // early-z slack: zp >= min(z)-5e-5 proven; 4x margin

// Value barrier: pins a value in a VGPR; no transform across it.
__device__ __forceinline__ float frn(float r) { asm("" : "+v"(r)); return r; }
__device__ __forceinline__ float mulrn(float a, float b) { return frn(a * b); }
__device__ __forceinline__ float addrn(float a, float b) { return frn(a + b); }
__device__ __forceinline__ float subrn(float a, float b) { return frn(a - b); }
__device__ __forceinline__ float divrn(float a, float b) { return frn(a / b); }
__device__ __forceinline__ float fmarn(float a, float b, float c) {
    return frn(__builtin_fmaf(a, b, c));
}

// ---------------------------------------------------------------------------
// Single-kernel rasterizer (R2 structure) + R3 fixes:
//  (1) Phase A face loads were 9 scalar dwords at 36B stride -> ~36 L1
//      line-transactions per load instr (issue-bound; R2 counters: VALUBusy
//      47%, HBM 3.7%, 42.5 us). Now each wave stages its 64 faces (2304 B,
//      16B-aligned: base = (cb + 64w)*36) into wave-private LDS with
//      2x float4 + 1x float fully-coalesced loads, then reads faces from LDS
//      (stride-9 words = 2-way bank alias = free per m136).
//  (2) Phase C no longer reloads the winner face (9 divergent loads) nor
//      redoes the 10-divide chain: phase B's win path computes bit-identical
//      n0,n1,n2,zp (same frn-pinned chains on the same constants; sd==det on
//      the win path since ins required |det|>TINYF), so we save
//      {n0,n1,n2,z0,z1,z2} at win-update and phase C is texture taps only.
// Numerics identical to the R2-passing kernel: same contracted chains, same
// inputs; tie-break (zp, then smaller index) is list-order-independent.
// LDS: 15360(s_abc) + 1280(s_i) + 4 + 9216(stage) ~= 25.9 KB -> 4 blocks/CU.
// ---------------------------------------------------------------------------
__global__ __launch_bounds__(256, 4) void fused_raster(
    const float* __restrict__ faces,
    const float* __restrict__ textures,
    float* __restrict__ out, int B, int F)
{
    const int tid  = threadIdx.x;
    const int lane = tid & 63;
    const int w    = tid >> 6;
    const int b    = blockIdx.x >> 8;
    const int tile = blockIdx.x & 255;
    const int TX   = tile & 15;        // 16-px tile coords (0..15)
    const int TY   = tile >> 4;

    __shared__ float4 s_a[CAP_T];
    __shared__ float4 s_b[CAP_T];
    __shared__ float4 s_c[CAP_T];
    __shared__ int    s_i[CAP_T];      // f | (quadmask << 12)
    __shared__ int    s_cnt;
    __shared__ float4 s_stage4[4][144];  // wave-private face staging (576 f32)

    if (tid == 0) s_cnt = 0;
    __syncthreads();

    // Quadrant pixel-center ranges (exact floats: small ints / 2^8).
    // Quadrant qx covers px in [16TX+8qx, 16TX+8qx+7], xp = (2px+1-256)/256 —
    // identical to the old 8x8 bin t=2TX+qx ranges.
    const float qxlo0 = (float)(32 * TX +  1 - 256) * (1.0f / 256.0f);
    const float qxhi0 = (float)(32 * TX + 15 - 256) * (1.0f / 256.0f);
    const float qxlo1 = (float)(32 * TX + 17 - 256) * (1.0f / 256.0f);
    const float qxhi1 = (float)(32 * TX + 31 - 256) * (1.0f / 256.0f);
    const float qylo0 = (float)(32 * TY +  1 - 256) * (1.0f / 256.0f);
    const float qyhi0 = (float)(32 * TY + 15 - 256) * (1.0f / 256.0f);
    const float qylo1 = (float)(32 * TY + 17 - 256) * (1.0f / 256.0f);
    const float qyhi1 = (float)(32 * TY + 31 - 256) * (1.0f / 256.0f);

    // ---- phase A: local bin — scan all faces of image b -------------------
    // Escape bound: fp-inside region extends <= ~6e-8/|det| beyond the hull;
    // dilate 2e-3 + 3e-7/|det| (5x safety, <= 0.032). |det| < 1e-5 ->
    // unbounded escape -> conservatively cover all 4 quadrants.
    const float* fimg = faces + (size_t)b * F * 9;
    float* stage = (float*)&s_stage4[w][0];
    for (int cb = 0; cb < F; cb += 256) {
        const int fw = cb + w * 64;                 // this wave's 64-face base
        const float* src = fimg + (size_t)fw * 9;   // 16B-aligned (fw%64==0)
        // Coalesced stage: 576 floats per wave = 2 float4 + 1 float per lane.
        const float4* src4 = (const float4*)src;
        const float4 v0 = src4[lane];
        const float4 v1 = src4[64 + lane];
        const float  v2 = src[512 + lane];
        s_stage4[w][lane]      = v0;
        s_stage4[w][64 + lane] = v1;
        stage[512 + lane]      = v2;
        __builtin_amdgcn_wave_barrier();  // order LDS write -> read (free)

        const float* fp = stage + lane * 9;   // stride-9 words: 2-way = free
        const float x0 = fp[0], y0 = fp[1], z0 = fp[2];
        const float x1 = fp[3], y1 = fp[4], z1 = fp[5];
        const float x2 = fp[6], y2 = fp[7], z2 = fp[8];

        const float det = (x1 - x0) * (y2 - y0) - (x2 - x0) * (y1 - y0);
        const float ad = fabsf(det);
        int mask;
        if (ad < DET_GLOBAL) {
            mask = 0xF;
        } else {
            const float d = 2e-3f + 3e-7f / ad;   // <= 0.032
            const float lox = fminf(x0, fminf(x1, x2)) - d;
            const float hix = fmaxf(x0, fmaxf(x1, x2)) + d;
            const float loy = fminf(y0, fminf(y1, y2)) - d;
            const float hiy = fmaxf(y0, fmaxf(y1, y2)) + d;
            // Dilation d (>= 2e-3 = 0.5 NDC px) dwarfs the ~1e-7 fp slack of
            // these compares (same argument as the old ceil/floor bin bounds).
            const bool ox0 = (hix >= qxlo0) && (lox <= qxhi0);
            const bool ox1 = (hix >= qxlo1) && (lox <= qxhi1);
            const bool oy0 = (hiy >= qylo0) && (loy <= qyhi0);
            const bool oy1 = (hiy >= qylo1) && (loy <= qyhi1);
            mask = ((ox0 && oy0) ? 1 : 0) | ((ox1 && oy0) ? 2 : 0)
                 | ((ox0 && oy1) ? 4 : 0) | ((ox1 && oy1) ? 8 : 0);
        }
        if (mask) {
            // Verified contracted numerics: C = fma(xa, yb, -(xb*ya)).
            const float A0 = subrn(x2, x1), B0 = subrn(y1, y2);
            const float C0 = fmarn(x1, y2, -mulrn(x2, y1));
            const float A1 = subrn(x0, x2), B1 = subrn(y2, y0);
            const float C1 = fmarn(x2, y0, -mulrn(x0, y2));
            const float A2 = subrn(x1, x0), B2 = subrn(y0, y1);
            const float C2 = fmarn(x0, y1, -mulrn(x1, y0));
            const int pos = atomicAdd(&s_cnt, 1);
            if (pos < CAP_T) {
                s_a[pos] = make_float4(A0, B0, C0, A1);
                s_b[pos] = make_float4(B1, C1, A2, B2);
                s_c[pos] = make_float4(C2, z0, z1, z2);
                s_i[pos] = (fw + lane) | (mask << 12);
            }
        }
        __builtin_amdgcn_wave_barrier();  // face read done before next stage
    }
    __syncthreads();
    const int cnt = min(s_cnt, CAP_T);

    // ---- phase B: rasterize — wave w owns one 8x8 quadrant ----------------
    // Early-z: skip the 10-divide chain when min(z) > bestz + ZEPS (cannot win
    // or tie). Tie-break (zp, then smaller index) matches the reference's
    // chunked argmin regardless of list order.
    const int qtx = 2 * TX + (w & 1);
    const int qty = 2 * TY + (w >> 1);
    const int px  = qtx * 8 + (lane & 7);
    const int py  = qty * 8 + (lane >> 3);
    const float xp = (float)(2 * px + 1 - IS) * (1.0f / IS);  // exact (/2^8)
    const float yp = (float)(2 * py + 1 - IS) * (1.0f / IS);  // exact
    const int qbit = 1 << (12 + w);

    float bestz = FARP;
    int   besti = -1;
    float bn0 = 0.f, bn1 = 0.f, bn2 = 0.f;     // winner's normalized weights
    float bz0 = 1.f, bz1 = 1.f, bz2 = 1.f;     // winner's vertex depths

    for (int j = 0; j < cnt; ++j) {
        const int mi = s_i[j];
        if (!(mi & qbit)) continue;          // wave-uniform skip
        const float4 fa  = s_a[j];
        const float4 fb4 = s_b[j];
        const float4 fc  = s_c[j];
        // Contracted: w = fma(yp, A, xp*B) + C
        const float w0 = addrn(fmarn(yp, fa.x, mulrn(xp, fa.y)), fa.z);
        const float w1 = addrn(fmarn(yp, fa.w, mulrn(xp, fb4.x)), fb4.y);
        const float w2 = addrn(fmarn(yp, fb4.z, mulrn(xp, fb4.w)), fc.x);
        const float det = addrn(addrn(w0, w1), w2);
        bool ins;
        if (det > TINYF)       ins = (w0 > 0.f) && (w1 > 0.f) && (w2 > 0.f);
        else if (det < -TINYF) ins = (w0 < 0.f) && (w1 < 0.f) && (w2 < 0.f);
        else                   ins = false;
        // Early-z: zp >= min(z) - ~5e-5 (clipped weights sum ~1), so a face
        // with min(z) > bestz+ZEPS can neither win nor tie.
        const float minz = fminf(fminf(fc.y, fc.z), fc.w);
        if (ins && minz <= bestz + ZEPS) {
            float n0 = divrn(w0, det), n1 = divrn(w1, det), n2 = divrn(w2, det);
            n0 = frn(fminf(fmaxf(n0, 0.f), 1.f));
            n1 = frn(fminf(fmaxf(n1, 0.f), 1.f));
            n2 = frn(fminf(fmaxf(n2, 0.f), 1.f));
            float s = addrn(addrn(n0, n1), n2);
            s = (s > TINYF) ? s : 1.0f;
            n0 = divrn(n0, s); n1 = divrn(n1, s); n2 = divrn(n2, s);
            float iz = addrn(addrn(divrn(n0, fc.y), divrn(n1, fc.z)),
                             divrn(n2, fc.w));
            iz = (fabsf(iz) > TINYF) ? iz : 1.0f;
            const float zp = divrn(1.0f, iz);
            if (zp > NEARP && zp < FARP) {
                const int fi = mi & 0xFFF;
                if (zp < bestz || (zp == bestz && fi < besti)) {
                    bestz = zp;
                    besti = fi;
                    bn0 = n0; bn1 = n1; bn2 = n2;
                    bz0 = fc.y; bz1 = fc.z; bz2 = fc.w;
                }
            }
        }
    }

    // ---- phase C: shade the winner from saved phase-B state ---------------
    // bn*/bz*/bestz are bit-identical to the old raw-coord recompute: the
    // phase-A constants chains equal the old phase-C inline chains op-for-op
    // (frn-pinned), and sd==det on the win path.
    float r = 0.f, g = 0.f, bch = 0.f, alpha = 0.f, depth = FARP;
    if (besti >= 0) {
        const float zp = bestz;
        depth = zp;
        const float t0 = fminf(fmaxf(divrn(mulrn(mulrn(bn0, 3.0f), zp), bz0), 0.f), 2.999f);
        const float t1 = fminf(fmaxf(divrn(mulrn(mulrn(bn1, 3.0f), zp), bz1), 0.f), 2.999f);
        const float t2 = fminf(fmaxf(divrn(mulrn(mulrn(bn2, 3.0f), zp), bz2), 0.f), 2.999f);
        const float l0 = floorf(t0), l1 = floorf(t1), l2 = floorf(t2);
        const float fr0 = subrn(t0, l0), fr1 = subrn(t1, l1), fr2 = subrn(t2, l2);
        const int i0 = (int)l0, i1 = (int)l1, i2 = (int)l2;

        const float* tx = textures + (size_t)(b * F + besti) * 64 * 3;
        for (int d0 = 0; d0 < 2; ++d0)
            for (int d1 = 0; d1 < 2; ++d1)
                for (int d2 = 0; d2 < 2; ++d2) {
                    const float wg = mulrn(mulrn(d0 ? fr0 : subrn(1.0f, fr0),
                                                 d1 ? fr1 : subrn(1.0f, fr1)),
                                           d2 ? fr2 : subrn(1.0f, fr2));
                    const float* tp = tx + ((i0 + d0) * 16 + (i1 + d1) * 4 + (i2 + d2)) * 3;
                    r   = addrn(r,   mulrn(wg, tp[0]));
                    g   = addrn(g,   mulrn(wg, tp[1]));
                    bch = addrn(bch, mulrn(wg, tp[2]));
                }
        alpha = 1.0f;
    }

    float* op = out + (((size_t)b * IS + py) * IS + px) * 5;
    op[0] = r;
    op[1] = g;
    op[2] = bch;
    op[3] = alpha;
    op[4] = depth;
}

extern "C" void kernel_launch(void* const* d_in, const int* in_sizes, int n_in,
                              void* d_out, int out_size, void* d_ws, size_t ws_size,
                              hipStream_t stream) {
    const float* faces    = (const float*)d_in[0];
    const float* textures = (const float*)d_in[1];
    float* out = (float*)d_out;
    const int F = FCOUNT;
    const int B = in_sizes[0] / (F * 9);

    fused_raster<<<dim3(B * 256), dim3(256), 0, stream>>>(
        faces, textures, out, B, F);
}

// Round 4
// 99.889 us; speedup vs baseline: 1.0036x; 1.0036x over previous
//
#include <hip/hip_runtime.h>

#define IS 256
#define FCOUNT 4096
#define NEARP 0.1f
#define FARP 100.0f
#define TINYF 1e-12f
#define CAP_P 320        // per-tile constants-pool capacity (mean ~60; proven R2/R3)
#define QCAP 192         // per-quadrant key-list capacity (mean ~27; proven R0 at 192)
#define DET_GLOBAL 1e-5f // |det| below this -> treat as covering all quadrants
#define ZEPS 2e-4f       // early-z slack: zp >= min(z)-5e-5 proven; 4x margin

// Value barrier: pins a value in a VGPR; no transform across it.
__device__ __forceinline__ float frn(float r) { asm("" : "+v"(r)); return r; }
__device__ __forceinline__ float mulrn(float a, float b) { return frn(a * b); }
__device__ __forceinline__ float addrn(float a, float b) { return frn(a + b); }
__device__ __forceinline__ float subrn(float a, float b) { return frn(a - b); }
__device__ __forceinline__ float divrn(float a, float b) { return frn(a / b); }
__device__ __forceinline__ float fmarn(float a, float b, float c) {
    return frn(__builtin_fmaf(a, b, c));
}

typedef unsigned long long u64;

__device__ __forceinline__ u64 shfl_u64(u64 v, int src) {
    const int lo = __shfl((int)(unsigned)v, src);
    const int hi = __shfl((int)(v >> 32), src);
    return ((u64)(unsigned)hi << 32) | (unsigned)lo;
}
__device__ __forceinline__ u64 shflx_u64(u64 v, int m) {
    const int lo = __shfl_xor((int)(unsigned)v, m);
    const int hi = __shfl_xor((int)(v >> 32), m);
    return ((u64)(unsigned)hi << 32) | (unsigned)lo;
}

// ---------------------------------------------------------------------------
// R4: sorted-z scan. R3 post-mortem: kernel is VALU-issue-bound (~5.9K
// instrs/wave), dominated by phase-B slow paths (10 IEEE divides each) that
// early-z fails to cull because faces arrive in arbitrary z order.
// Fix: per-quadrant key lists, key = (f32bits(minz)<<32)|(f<<9)|pos, each
// wave sorts its own <=64 keys in registers (21-round shfl_xor bitonic, no
// barriers), scans ascending-minz with a wave-uniform break when
// __all(minz > bestz+ZEPS) — sorted => all remaining faces are culled, exact.
// Overflow entries (>64/quadrant, ~10-sigma) are processed FIRST, unsorted:
// the argmin update (z then smaller-index tie-break) is order-independent,
// and the cull bound (zp >= minz - 5e-5, ZEPS=2e-4) is order-independent too,
// so any processing order yields bit-identical results. Accept-path numerics
// are op-for-op the R2/R3-verified frn-pinned chains; minz bits in the key
// equal phase-B's old fminf(fminf(z0,z1),z2). Slivers (|det|<1e-5) get all 4
// quadrants of the tile (= old scanned-by-everyone semantics).
// Phase C shades from phase-B-saved state (R3): no face reload, no divides.
// LDS: 15360(pool) + 6144(s_q) + 9216(stage) + 24 ~= 30.7 KB -> 4 blocks/CU.
// ---------------------------------------------------------------------------
__global__ __launch_bounds__(256, 4) void fused_raster(
    const float* __restrict__ faces,
    const float* __restrict__ textures,
    float* __restrict__ out, int B, int F)
{
    const int tid  = threadIdx.x;
    const int lane = tid & 63;
    const int w    = tid >> 6;
    const int b    = blockIdx.x >> 8;
    const int tile = blockIdx.x & 255;
    const int TX   = tile & 15;        // 16-px tile coords (0..15)
    const int TY   = tile >> 4;

    __shared__ float4 s_a[CAP_P];
    __shared__ float4 s_b[CAP_P];
    __shared__ float4 s_c[CAP_P];
    __shared__ u64    s_q[4][QCAP];    // per-quadrant sorted-scan keys
    __shared__ int    s_qcnt[4];
    __shared__ int    s_cnt;
    __shared__ float4 s_stage4[4][144];  // wave-private face staging (576 f32)

    if (tid == 0) s_cnt = 0;
    if (tid < 4)  s_qcnt[tid] = 0;
    __syncthreads();

    // Quadrant pixel-center ranges (exact floats: small ints / 2^8) —
    // identical to the old 8x8 bin ranges.
    const float qxlo0 = (float)(32 * TX +  1 - 256) * (1.0f / 256.0f);
    const float qxhi0 = (float)(32 * TX + 15 - 256) * (1.0f / 256.0f);
    const float qxlo1 = (float)(32 * TX + 17 - 256) * (1.0f / 256.0f);
    const float qxhi1 = (float)(32 * TX + 31 - 256) * (1.0f / 256.0f);
    const float qylo0 = (float)(32 * TY +  1 - 256) * (1.0f / 256.0f);
    const float qyhi0 = (float)(32 * TY + 15 - 256) * (1.0f / 256.0f);
    const float qylo1 = (float)(32 * TY + 17 - 256) * (1.0f / 256.0f);
    const float qyhi1 = (float)(32 * TY + 31 - 256) * (1.0f / 256.0f);

    // ---- phase A: local bin — scan all faces of image b -------------------
    // Escape bound: fp-inside region extends <= ~6e-8/|det| beyond the hull;
    // dilate 2e-3 + 3e-7/|det| (5x safety, <= 0.032). |det| < 1e-5 ->
    // unbounded escape -> conservatively cover all 4 quadrants.
    const float* fimg = faces + (size_t)b * F * 9;
    float* stage = (float*)&s_stage4[w][0];
    for (int cb = 0; cb < F; cb += 256) {
        const int fw = cb + w * 64;                 // this wave's 64-face base
        const float* src = fimg + (size_t)fw * 9;   // 16B-aligned (fw%64==0)
        const float4* src4 = (const float4*)src;
        const float4 v0 = src4[lane];
        const float4 v1 = src4[64 + lane];
        const float  v2 = src[512 + lane];
        s_stage4[w][lane]      = v0;
        s_stage4[w][64 + lane] = v1;
        stage[512 + lane]      = v2;
        __builtin_amdgcn_wave_barrier();  // order LDS write -> read (free)

        const float* fp = stage + lane * 9;   // stride-9 words: 2-way = free
        const float x0 = fp[0], y0 = fp[1], z0 = fp[2];
        const float x1 = fp[3], y1 = fp[4], z1 = fp[5];
        const float x2 = fp[6], y2 = fp[7], z2 = fp[8];

        const float det = (x1 - x0) * (y2 - y0) - (x2 - x0) * (y1 - y0);
        const float ad = fabsf(det);
        int mask;
        if (ad < DET_GLOBAL) {
            mask = 0xF;
        } else {
            const float d = 2e-3f + 3e-7f / ad;   // <= 0.032
            const float lox = fminf(x0, fminf(x1, x2)) - d;
            const float hix = fmaxf(x0, fmaxf(x1, x2)) + d;
            const float loy = fminf(y0, fminf(y1, y2)) - d;
            const float hiy = fmaxf(y0, fmaxf(y1, y2)) + d;
            // Dilation d (>= 2e-3 = 0.5 NDC px) dwarfs the ~1e-7 fp slack.
            const bool ox0 = (hix >= qxlo0) && (lox <= qxhi0);
            const bool ox1 = (hix >= qxlo1) && (lox <= qxhi1);
            const bool oy0 = (hiy >= qylo0) && (loy <= qyhi0);
            const bool oy1 = (hiy >= qylo1) && (loy <= qyhi1);
            mask = ((ox0 && oy0) ? 1 : 0) | ((ox1 && oy0) ? 2 : 0)
                 | ((ox0 && oy1) ? 4 : 0) | ((ox1 && oy1) ? 8 : 0);
        }
        if (mask) {
            // Verified contracted numerics: C = fma(xa, yb, -(xb*ya)).
            const float A0 = subrn(x2, x1), B0 = subrn(y1, y2);
            const float C0 = fmarn(x1, y2, -mulrn(x2, y1));
            const float A1 = subrn(x0, x2), B1 = subrn(y2, y0);
            const float C1 = fmarn(x2, y0, -mulrn(x0, y2));
            const float A2 = subrn(x1, x0), B2 = subrn(y0, y1);
            const float C2 = fmarn(x0, y1, -mulrn(x1, y0));
            const int pos = atomicAdd(&s_cnt, 1);
            if (pos < CAP_P) {
                s_a[pos] = make_float4(A0, B0, C0, A1);
                s_b[pos] = make_float4(B1, C1, A2, B2);
                s_c[pos] = make_float4(C2, z0, z1, z2);
                // minz bits == phase-B's old fminf(fminf(z0,z1),z2).
                const float minz = fminf(fminf(z0, z1), z2);
                const u64 key = ((u64)__float_as_uint(minz) << 32)
                              | (unsigned)(((fw + lane) << 9) | pos);
                #pragma unroll
                for (int q = 0; q < 4; ++q)
                    if (mask & (1 << q)) {
                        const int qp = atomicAdd(&s_qcnt[q], 1);
                        if (qp < QCAP) s_q[q][qp] = key;
                    }
            }
        }
        __builtin_amdgcn_wave_barrier();  // face read done before next stage
    }
    __syncthreads();

    // ---- phase B: rasterize — wave w owns one 8x8 quadrant ----------------
    const int qtx = 2 * TX + (w & 1);
    const int qty = 2 * TY + (w >> 1);
    const int px  = qtx * 8 + (lane & 7);
    const int py  = qty * 8 + (lane >> 3);
    const float xp = (float)(2 * px + 1 - IS) * (1.0f / IS);  // exact (/2^8)
    const float yp = (float)(2 * py + 1 - IS) * (1.0f / IS);  // exact

    float bestz = FARP;
    int   besti = -1;
    float bn0 = 0.f, bn1 = 0.f, bn2 = 0.f;     // winner's normalized weights
    float bz0 = 1.f, bz1 = 1.f, bz2 = 1.f;     // winner's vertex depths

    const int qcnt = min(s_qcnt[w], QCAP);

    // Shared face-evaluate + argmin-update (R2/R3-verified chain, verbatim).
    auto process = [&](u64 key) {
        const int  pos  = (int)(key & 0x1FF);
        const float minz = __uint_as_float((unsigned)(key >> 32));
        const float4 fa  = s_a[pos];
        const float4 fb4 = s_b[pos];
        const float4 fc  = s_c[pos];
        // Contracted: w = fma(yp, A, xp*B) + C
        const float w0 = addrn(fmarn(yp, fa.x, mulrn(xp, fa.y)), fa.z);
        const float w1 = addrn(fmarn(yp, fa.w, mulrn(xp, fb4.x)), fb4.y);
        const float w2 = addrn(fmarn(yp, fb4.z, mulrn(xp, fb4.w)), fc.x);
        const float det = addrn(addrn(w0, w1), w2);
        bool ins;
        if (det > TINYF)       ins = (w0 > 0.f) && (w1 > 0.f) && (w2 > 0.f);
        else if (det < -TINYF) ins = (w0 < 0.f) && (w1 < 0.f) && (w2 < 0.f);
        else                   ins = false;
        // Early-z: zp >= min(z) - ~5e-5, so minz > bestz+ZEPS cannot win/tie.
        if (ins && minz <= bestz + ZEPS) {
            float n0 = divrn(w0, det), n1 = divrn(w1, det), n2 = divrn(w2, det);
            n0 = frn(fminf(fmaxf(n0, 0.f), 1.f));
            n1 = frn(fminf(fmaxf(n1, 0.f), 1.f));
            n2 = frn(fminf(fmaxf(n2, 0.f), 1.f));
            float s = addrn(addrn(n0, n1), n2);
            s = (s > TINYF) ? s : 1.0f;
            n0 = divrn(n0, s); n1 = divrn(n1, s); n2 = divrn(n2, s);
            float iz = addrn(addrn(divrn(n0, fc.y), divrn(n1, fc.z)),
                             divrn(n2, fc.w));
            iz = (fabsf(iz) > TINYF) ? iz : 1.0f;
            const float zp = divrn(1.0f, iz);
            if (zp > NEARP && zp < FARP) {
                const int fi = (int)((key >> 9) & 0xFFF);
                if (zp < bestz || (zp == bestz && fi < besti)) {
                    bestz = zp;
                    besti = fi;
                    bn0 = n0; bn1 = n1; bn2 = n2;
                    bz0 = fc.y; bz1 = fc.z; bz2 = fc.w;
                }
            }
        }
    };

    // Overflow part first (unsorted, order-independent): entries 64..qcnt-1.
    for (int j = 64; j < qcnt; ++j) process(s_q[w][j]);

    // Sorted main part: each wave sorts its <=64 keys in registers.
    u64 v = (lane < qcnt) ? s_q[w][lane] : 0x7F800000FFFFFFFFULL; // +inf pad
    #pragma unroll
    for (int k = 2; k <= 64; k <<= 1)
        #pragma unroll
        for (int j = k >> 1; j > 0; j >>= 1) {
            const u64 o = shflx_u64(v, j);
            const bool up  = ((lane & k) == 0);
            const bool low = ((lane & j) == 0);
            const bool takeMin = (up == low);
            const u64 mn = (v < o) ? v : o;
            const u64 mx = (v < o) ? o : v;
            v = takeMin ? mn : mx;
        }
    const int scnt = min(qcnt, 64);
    for (int j = 0; j < scnt; ++j) {
        const u64 key = shfl_u64(v, j);
        const float minz = __uint_as_float((unsigned)(key >> 32));
        // Sorted => all remaining faces have minz' >= minz: if every lane
        // culls this one, every lane culls all the rest. Exact break.
        if (__all(minz > bestz + ZEPS)) break;
        process(key);
    }

    // ---- phase C: shade the winner from saved phase-B state ---------------
    float r = 0.f, g = 0.f, bch = 0.f, alpha = 0.f, depth = FARP;
    if (besti >= 0) {
        const float zp = bestz;
        depth = zp;
        const float t0 = fminf(fmaxf(divrn(mulrn(mulrn(bn0, 3.0f), zp), bz0), 0.f), 2.999f);
        const float t1 = fminf(fmaxf(divrn(mulrn(mulrn(bn1, 3.0f), zp), bz1), 0.f), 2.999f);
        const float t2 = fminf(fmaxf(divrn(mulrn(mulrn(bn2, 3.0f), zp), bz2), 0.f), 2.999f);
        const float l0 = floorf(t0), l1 = floorf(t1), l2 = floorf(t2);
        const float fr0 = subrn(t0, l0), fr1 = subrn(t1, l1), fr2 = subrn(t2, l2);
        const int i0 = (int)l0, i1 = (int)l1, i2 = (int)l2;

        const float* tx = textures + (size_t)(b * F + besti) * 64 * 3;
        for (int d0 = 0; d0 < 2; ++d0)
            for (int d1 = 0; d1 < 2; ++d1)
                for (int d2 = 0; d2 < 2; ++d2) {
                    const float wg = mulrn(mulrn(d0 ? fr0 : subrn(1.0f, fr0),
                                                 d1 ? fr1 : subrn(1.0f, fr1)),
                                           d2 ? fr2 : subrn(1.0f, fr2));
                    const float* tp = tx + ((i0 + d0) * 16 + (i1 + d1) * 4 + (i2 + d2)) * 3;
                    r   = addrn(r,   mulrn(wg, tp[0]));
                    g   = addrn(g,   mulrn(wg, tp[1]));
                    bch = addrn(bch, mulrn(wg, tp[2]));
                }
        alpha = 1.0f;
    }

    float* op = out + (((size_t)b * IS + py) * IS + px) * 5;
    op[0] = r;
    op[1] = g;
    op[2] = bch;
    op[3] = alpha;
    op[4] = depth;
}

extern "C" void kernel_launch(void* const* d_in, const int* in_sizes, int n_in,
                              void* d_out, int out_size, void* d_ws, size_t ws_size,
                              hipStream_t stream) {
    const float* faces    = (const float*)d_in[0];
    const float* textures = (const float*)d_in[1];
    float* out = (float*)d_out;
    const int F = FCOUNT;
    const int B = in_sizes[0] / (F * 9);

    fused_raster<<<dim3(B * 256), dim3(256), 0, stream>>>(
        faces, textures, out, B, F);
}